// Round 6
// baseline (226.534 us; speedup 1.0000x reference)
//
#include <hip/hip_runtime.h>
#include <math.h>

#ifndef __has_builtin
#define __has_builtin(x) 0
#endif

#if __has_builtin(__builtin_amdgcn_rcpf)
#define FAST_RCP(x) __builtin_amdgcn_rcpf(x)
#else
#define FAST_RCP(x) (1.0f / (x))
#endif

#if __has_builtin(__builtin_amdgcn_exp2f)
#define FAST_EXP2(x) __builtin_amdgcn_exp2f(x)
#else
#define FAST_EXP2(x) exp2f(x)
#endif

typedef _Float16 half8 __attribute__((ext_vector_type(8)));
typedef float f32x4 __attribute__((ext_vector_type(4)));
typedef float f32x2 __attribute__((ext_vector_type(2)));

constexpr int T_STEPS = 180;
constexpr int I_DIM   = 7;
constexpr int HDIM    = 64;
constexpr int BT      = 16;     // batch tile per block
constexpr int NCH     = 12;     // 12 chunks x 8 halfs = 96 K rows
constexpr int CH_HALF = BT * 8; // halfs per chunk slice (=128)
constexpr int XSTR    = 136;    // halfs per xstage t-slice (17 granules)

// ---- R6: 32 waves/CU (1 tile per wave) ----
// TLP ranking measured: 8 waves/CU -> 156us (R5), 16 -> 135us (R3); no pipe
// saturated at R3 (VALU 57 / MFMA 22 / LDS ~30%) => fill-limited. BT=16 is
// fixed by grid>=2/CU, so block=1024 threads (16 waves), grid 512 ->
// 2 blocks/CU, 32 waves/CU, 8 waves/SIMD (2x R3), 100% occupancy target.
// Each wave owns ONE 16-row A-tile: A-row r -> gate = r&3, unit = 4w+(r>>2).
// C-row of lane (q,n15), reg j is 4q+j  =>  acc = {i,f,g,o} of unit 4w+q:
// ONE complete cell per thread, scalar cell math (packed pairing impossible
// at 1 cell/thread; VALU floor ~90us, LDS b128 floor ~94us -- both << 135).
// Per wave/step: 3 ds_read_b128 + 3 MFMA (2+1 partial-acc split to shorten
// the dep chain) + scalar cell + 1 ds_write_b16 + barrier. VGPR ~50 -> cap
// 64 via __launch_bounds__(1024, 8) keeps both blocks resident.
// All validated structure kept: chunk-major conflict-free B reads (R1),
// zero-vmem steady loop + lane-blended x feed (R2), exp2-scale folding +
// shared-denominator cell (5 exp2 + 2 rcp). xstage holds ALL 180 steps
// (59.4KB LDS/block < 64KB; 2 blocks = 119KB/CU) -- no restage barrier.
__global__ __launch_bounds__(1024, 8) void lstm_mfma_kernel(
    const float* __restrict__ x,
    const float* __restrict__ W_ih,
    const float* __restrict__ W_hh,
    const float* __restrict__ b_ih,
    const float* __restrict__ b_hh,
    const float* __restrict__ W_fc,
    const float* __restrict__ b_fc,
    float* __restrict__ out) {
    __shared__ alignas(16) _Float16 Bbuf[2][NCH][BT][8];
    __shared__ alignas(16) _Float16 xstage[T_STEPS * XSTR];
    __shared__ alignas(16) float hlds[BT][HDIM + 4];

    const int tid  = (int)threadIdx.x;
    const int w    = tid >> 6;    // wave 0..15
    const int lane = tid & 63;
    const int q    = lane >> 4;   // quad 0..3
    const int n15  = lane & 15;   // batch col within tile
    const long bbase = (long)blockIdx.x * BT;

    // ---- A fragment (single tile per wave), scale-folded ----
    // This lane supplies A-row n15: gate = n15&3, unit = 4w + (n15>>2).
    half8 afrag[3];
    {
        const int gate = n15 & 3;
        const int unit = 4 * w + (n15 >> 2);
        const int grow = gate * HDIM + unit;  // row in PyTorch [4H, *] params
        const float scl = (gate == 2) ? 2.88539008177792681472f
                                      : -1.44269504088896340736f;
#pragma unroll
        for (int kc = 0; kc < 3; ++kc) {
#pragma unroll
            for (int j = 0; j < 8; ++j) {
                const int k = kc * 32 + q * 8 + j;
                float v;
                if (k < I_DIM)            v = W_ih[grow * I_DIM + k];
                else if (k == I_DIM)      v = b_ih[grow] + b_hh[grow];
                else if (k < 8 + HDIM)    v = W_hh[grow * HDIM + (k - 8)];
                else                      v = 0.0f;
                afrag[kc][j] = (_Float16)(scl * v);
            }
        }
    }

    // ---- prologue: stage ALL x into LDS (f16, fragment layout) ----
    // slice t: [n*8+i] = x_t[n][i] for i<7; [n*8+7] = 1.0 (bias col).
    for (int idx = tid; idx < BT * T_STEPS * 8; idx += 1024) {
        const int i = idx & 7;
        const int n = (idx >> 3) & 15;
        const int t = idx >> 7;
        float v = 1.0f;
        if (i < I_DIM)
            v = x[(bbase + n) * (T_STEPS * I_DIM) + t * I_DIM + i];
        xstage[t * XSTR + n * 8 + i] = (_Float16)v;
    }
    // zero both B buffers (h_0 = 0; pad chunks must not be NaN)
    for (int idx = tid; idx < 2 * NCH * CH_HALF; idx += 1024)
        ((_Float16*)Bbuf)[idx] = (_Float16)0.0f;
    __syncthreads();

    // cell ownership: unit u = 4w + q (one cell per thread)
    const int u = 4 * w + q;

    // hoisted LDS pointers (bf0 lane-blended: q==0 lanes walk xstage)
    const _Float16* const rb0 = &Bbuf[0][q][n15][0];
    const _Float16* const rb1 = &Bbuf[1][q][n15][0];
    const _Float16* xb0 = (q == 0) ? &xstage[0 * XSTR + n15 * 8] : rb0;
    const _Float16* xb1 = (q == 0) ? &xstage[1 * XSTR + n15 * 8] : rb1;
    const int xadv = (q == 0) ? 2 * XSTR : 0;
    _Float16* const hw0 = &Bbuf[0][1 + (u >> 3)][n15][u & 7];
    _Float16* const hw1 = &Bbuf[1][1 + (u >> 3)][n15][u & 7];

    float c = 0.0f, h = 0.0f;
    const f32x4 zq = {0.0f, 0.0f, 0.0f, 0.0f};

    // Scalar cell: acc = {i',f',g',o'} exp2-ready.
    //   A=2^i', F=2^f', E=2^g', O=2^o'
    //   c' = (c*P + (E-1)*Q) * rcp(P*Q),  P=(1+A)(E+1), Q=1+F
    //   h  = (C-1) * rcp((1+O)(C+1)),     C=2^(k*c') clamped
#define LSTM_CELL(ACC)                                                         \
    {                                                                          \
        const float A = FAST_EXP2(ACC[0]);                                     \
        const float F = FAST_EXP2(ACC[1]);                                     \
        const float E = FAST_EXP2(ACC[2]);                                     \
        const float P = (1.0f + A) * (E + 1.0f);                               \
        const float Q = 1.0f + F;                                              \
        const float R = FAST_RCP(P * Q);                                       \
        c = (c * P + (E - 1.0f) * Q) * R;                                      \
        const float O = FAST_EXP2(ACC[3]);                                     \
        float cs = 2.88539008177792681472f * c;                                \
        cs = fminf(fmaxf(cs, -80.0f), 80.0f);                                  \
        const float C = FAST_EXP2(cs);                                         \
        h = (C - 1.0f) * FAST_RCP((1.0f + O) * (C + 1.0f));                    \
    }

    // One timestep: 3 ds_read_b128, 3 MFMA (2+1 split), cell, b16 h-write.
#define LSTM_STEP(RB, XB, HW)                                                  \
    {                                                                          \
        const half8 bf0 = *(const half8*)(XB);                                 \
        const half8 bf1 = *(const half8*)((RB) + 4 * CH_HALF);                 \
        const half8 bf2 = *(const half8*)((RB) + 8 * CH_HALF);                 \
        f32x4 accA = __builtin_amdgcn_mfma_f32_16x16x32_f16(afrag[0], bf0, zq, 0, 0, 0); \
        f32x4 accB = __builtin_amdgcn_mfma_f32_16x16x32_f16(afrag[2], bf2, zq, 0, 0, 0); \
        accA = __builtin_amdgcn_mfma_f32_16x16x32_f16(afrag[1], bf1, accA, 0, 0, 0); \
        const f32x4 acc = accA + accB;                                         \
        LSTM_CELL(acc)                                                         \
        *(HW) = (_Float16)h;                                                   \
        __syncthreads();                                                       \
    }

    for (int t = 0; t < T_STEPS; t += 2) {
        LSTM_STEP(rb0, xb0, hw1)       // read buf0 (+ xstage[t]),   write buf1
        LSTM_STEP(rb1, xb1, hw0)       // read buf1 (+ xstage[t+1]), write buf0
        xb0 += xadv;
        xb1 += xadv;
    }
#undef LSTM_STEP
#undef LSTM_CELL

    // ---- epilogue: out[b][j] = b_fc[j] + sum_u h[b][u] * W_fc[j][u] ----
    hlds[n15][u] = h;   // 1024 threads = 16 x 64: exact cover
    __syncthreads();
    if (tid < 256) {
        const int b = tid >> 4, j = tid & 15;
        float s = b_fc[j];
#pragma unroll 8
        for (int uu = 0; uu < HDIM; ++uu)
            s += hlds[b][uu] * W_fc[j * HDIM + uu];
        out[(bbase + b) * 16 + j] = s;
    }
}

extern "C" void kernel_launch(void* const* d_in, const int* in_sizes, int n_in,
                              void* d_out, int out_size, void* d_ws, size_t ws_size,
                              hipStream_t stream) {
    const float* x    = (const float*)d_in[0];
    const float* W_ih = (const float*)d_in[1];
    const float* W_hh = (const float*)d_in[2];
    const float* b_ih = (const float*)d_in[3];
    const float* b_hh = (const float*)d_in[4];
    const float* W_fc = (const float*)d_in[5];
    const float* b_fc = (const float*)d_in[6];
    float* out = (float*)d_out;

    const int B = in_sizes[0] / (T_STEPS * I_DIM);  // 8192
    const int grid = B / BT;                         // 512 blocks (2/CU)

    lstm_mfma_kernel<<<grid, 1024, 0, stream>>>(x, W_ih, W_hh, b_ih, b_hh,
                                                W_fc, b_fc, out);
}

// Round 7
// 194.739 us; speedup vs baseline: 1.1633x; 1.1633x over previous
//
#include <hip/hip_runtime.h>
#include <math.h>

#ifndef __has_builtin
#define __has_builtin(x) 0
#endif

#if __has_builtin(__builtin_amdgcn_rcpf)
#define FAST_RCP(x) __builtin_amdgcn_rcpf(x)
#else
#define FAST_RCP(x) (1.0f / (x))
#endif

#if __has_builtin(__builtin_amdgcn_exp2f)
#define FAST_EXP2(x) __builtin_amdgcn_exp2f(x)
#else
#define FAST_EXP2(x) exp2f(x)
#endif

typedef _Float16 half8 __attribute__((ext_vector_type(8)));
typedef _Float16 half2v __attribute__((ext_vector_type(2)));
typedef float f32x4 __attribute__((ext_vector_type(4)));
typedef float f32x2 __attribute__((ext_vector_type(2)));

constexpr int T_STEPS = 180;
constexpr int I_DIM   = 7;
constexpr int HDIM    = 64;
constexpr int BT      = 16;     // batch tile per block
constexpr int CH_HALF = BT * 8; // halfs per chunk slice (=128)
constexpr int XSTR    = 136;    // halfs per xstage t-slice (17 granules)

// ---- R7: hoist the h-independent GEMM part across the barrier ----
// Convoy diagnosis (R3..R6): interval ~900cy/block-step vs ~320-500cy max
// single-pipe demand; TLP axis mapped (8/16/32 waves/CU -> 156/135/176us):
// the loss is the post-barrier serial chain (3 ds_read -> 3-deep MFMA ->
// trans cell chain -> write -> drain) walked 180 times.
// Fix: k-layout [x(7)+bias | 24 zero | h(64)] so chunk 0 is h-INDEPENDENT.
// Step t's body computes step t+1's chunk-0 MFMAs (xstage read, zero deps)
// and carries them across the barrier as the accumulator C-input. Post-
// barrier chain: 2 reads + 2-deep MFMA (was 3 + 3-deep); LDS burst 24->16
// b128/block. Chunk-0 A-rows k>=8 are ZERO, so the bfx B-fragment can be a
// uniform broadcast read of xstage (no lane-blend; garbage x 0 = 0).
// s_setprio(1) wraps the critical chain (2 phase-diverse blocks/CU = T5's
// favorable regime); sched_barrier(0) pins hoisted MFMAs before the sync.
// Everything validated kept: chunk-major conflict-free h reads (R1), zero
// steady-state vmem (R2), gate-pair remap + packed dual-f32 cell (R3),
// 8-wave/512-thread blocks at 2 blocks/CU (R4/R5/R6 ablations).
// A-row remap: tile pt, row r -> param row gate*64 + unit,
//   gate = 2*pt + ((r>>1)&1), unit = 8w + 2*(r>>2) + (r&1)
// => lane (q,n15): acc0 = {i(u0),i(u0+1),f(u0),f(u0+1)},
//    acc1 = {g..,o..}, u0 = 8w+2q; h stored as ONE packed b32 write.
__global__ __launch_bounds__(512, 4) void lstm_mfma_kernel(
    const float* __restrict__ x,
    const float* __restrict__ W_ih,
    const float* __restrict__ W_hh,
    const float* __restrict__ b_ih,
    const float* __restrict__ b_hh,
    const float* __restrict__ W_fc,
    const float* __restrict__ b_fc,
    float* __restrict__ out) {
    __shared__ alignas(16) _Float16 Bbuf[2][8][BT][8];       // h only (k=32..96)
    __shared__ alignas(16) _Float16 xstage[(T_STEPS + 1) * XSTR];
    __shared__ alignas(16) float hlds[BT][HDIM + 4];

    const int tid  = (int)threadIdx.x;
    const int w    = tid >> 6;    // wave 0..7
    const int lane = tid & 63;
    const int q    = lane >> 4;   // quad 0..3
    const int n15  = lane & 15;   // batch col within tile
    const long bbase = (long)blockIdx.x * BT;

    // ---- A fragments, scale-folded, gate-pair remap; new k-layout ----
    // kc=0: k=8q+j: q==0 -> x weights (j<7) / bias (j==7); q>=1 -> ZERO.
    // kc=1,2: h unit uu = 32*(kc-1)+8q+j -> W_hh[grow][uu].
    half8 afrag[2][3];
#pragma unroll
    for (int pt = 0; pt < 2; ++pt) {
        const int gate = 2 * pt + ((n15 >> 1) & 1);
        const int unit = 8 * w + 2 * (n15 >> 2) + (n15 & 1);
        const int grow = gate * HDIM + unit;  // row in PyTorch [4H, *] params
        const float scl = (gate == 2) ? 2.88539008177792681472f
                                      : -1.44269504088896340736f;
#pragma unroll
        for (int kc = 0; kc < 3; ++kc) {
#pragma unroll
            for (int j = 0; j < 8; ++j) {
                float v;
                if (kc == 0) {
                    if (q != 0)          v = 0.0f;
                    else if (j < I_DIM)  v = W_ih[grow * I_DIM + j];
                    else                 v = b_ih[grow] + b_hh[grow];
                } else {
                    v = W_hh[grow * HDIM + (kc - 1) * 32 + 8 * q + j];
                }
                afrag[pt][kc][j] = (_Float16)(scl * v);
            }
        }
    }

    // ---- prologue: stage all x (+1 zero slice) into LDS ----
    // slice t: [n*8+i] = x_t[n][i] (i<7); [n*8+7] = 1.0 (bias col).
    for (int idx = tid; idx < BT * (T_STEPS + 1) * 8; idx += 512) {
        const int i = idx & 7;
        const int n = (idx >> 3) & 15;
        const int t = idx >> 7;
        float v = 1.0f;
        if (i < I_DIM)
            v = (t < T_STEPS)
                    ? x[(bbase + n) * (T_STEPS * I_DIM) + t * I_DIM + i]
                    : 0.0f;
        xstage[t * XSTR + n * 8 + i] = (_Float16)v;
    }
    // zero both h buffers (h_0 = 0)
    for (int idx = tid; idx < 2 * 8 * CH_HALF; idx += 512)
        ((_Float16*)Bbuf)[idx] = (_Float16)0.0f;
    __syncthreads();

    // cell ownership: units u0 = 8w+2q, u0+1 (adjacent)
    const int u0 = 8 * w + 2 * q;

    // hoisted LDS pointers. bf1: chunk q (k=32..64); bf2: chunk 4+q.
    const _Float16* const rb0 = &Bbuf[0][q][n15][0];
    const _Float16* const rb1 = &Bbuf[1][q][n15][0];
    half2v* const hw0 = (half2v*)&Bbuf[0][w][n15][2 * q];
    half2v* const hw1 = (half2v*)&Bbuf[1][w][n15][2 * q];
    // bfx: uniform broadcast read of xstage slice (all q read same n15 addr)
    const _Float16* xb = &xstage[XSTR + n15 * 8];   // slice t+1, starts at 1

    f32x2 cp = {0.0f, 0.0f};
    f32x2 hp = {0.0f, 0.0f};
    const f32x4 zq = {0.0f, 0.0f, 0.0f, 0.0f};

    // Packed cell: acc0={i0,i1,f0,f1}, acc1={g0,g1,o0,o1} (exp2-ready).
#define LSTM_CELL2(A0, A1)                                                     \
    {                                                                          \
        f32x2 Ap, Fp, Ep, Op, Rp, Cp, rD;                                      \
        Ap[0] = FAST_EXP2(A0[0]); Ap[1] = FAST_EXP2(A0[1]);                    \
        Fp[0] = FAST_EXP2(A0[2]); Fp[1] = FAST_EXP2(A0[3]);                    \
        Ep[0] = FAST_EXP2(A1[0]); Ep[1] = FAST_EXP2(A1[1]);                    \
        const f32x2 Pp = (Ap + 1.0f) * (Ep + 1.0f);                            \
        const f32x2 Qp = Fp + 1.0f;                                            \
        const f32x2 PQ = Pp * Qp;                                              \
        Rp[0] = FAST_RCP(PQ[0]); Rp[1] = FAST_RCP(PQ[1]);                      \
        cp = (cp * Pp + (Ep - 1.0f) * Qp) * Rp;                                \
        Op[0] = FAST_EXP2(A1[2]); Op[1] = FAST_EXP2(A1[3]);                    \
        f32x2 cs = cp * 2.88539008177792681472f;                               \
        cs[0] = fminf(fmaxf(cs[0], -80.0f), 80.0f);                            \
        cs[1] = fminf(fmaxf(cs[1], -80.0f), 80.0f);                            \
        Cp[0] = FAST_EXP2(cs[0]); Cp[1] = FAST_EXP2(cs[1]);                    \
        const f32x2 Dp = (Op + 1.0f) * (Cp + 1.0f);                            \
        rD[0] = FAST_RCP(Dp[0]); rD[1] = FAST_RCP(Dp[1]);                      \
        hp = (Cp - 1.0f) * rD;                                                 \
    }

    // x-part of step 0 (h-independent), issued before entering the loop.
    f32x4 nacc0, nacc1;
    {
        const half8 bfx0 = *(const half8*)&xstage[0 * XSTR + n15 * 8];
        nacc0 = __builtin_amdgcn_mfma_f32_16x16x32_f16(afrag[0][0], bfx0, zq, 0, 0, 0);
        nacc1 = __builtin_amdgcn_mfma_f32_16x16x32_f16(afrag[1][0], bfx0, zq, 0, 0, 0);
    }

    // One step: post-barrier = 2 reads + 2-deep MFMA + cell + write.
    // Inside the body: issue step t+1's x-part (bfx read + 2 MFMAs, no deps).
#define LSTM_STEP(RB, HW, XO)                                                  \
    {                                                                          \
        __builtin_amdgcn_s_setprio(1);                                         \
        const half8 bf1 = *(const half8*)(RB);                                 \
        const half8 bf2 = *(const half8*)((RB) + 4 * CH_HALF);                 \
        f32x4 acc0 = __builtin_amdgcn_mfma_f32_16x16x32_f16(afrag[0][1], bf1, nacc0, 0, 0, 0); \
        f32x4 acc1 = __builtin_amdgcn_mfma_f32_16x16x32_f16(afrag[1][1], bf1, nacc1, 0, 0, 0); \
        acc0 = __builtin_amdgcn_mfma_f32_16x16x32_f16(afrag[0][2], bf2, acc0, 0, 0, 0); \
        acc1 = __builtin_amdgcn_mfma_f32_16x16x32_f16(afrag[1][2], bf2, acc1, 0, 0, 0); \
        const half8 bfx = *(const half8*)(xb + (XO));                          \
        nacc0 = __builtin_amdgcn_mfma_f32_16x16x32_f16(afrag[0][0], bfx, zq, 0, 0, 0); \
        nacc1 = __builtin_amdgcn_mfma_f32_16x16x32_f16(afrag[1][0], bfx, zq, 0, 0, 0); \
        LSTM_CELL2(acc0, acc1)                                                 \
        *(HW) = (half2v){(_Float16)hp[0], (_Float16)hp[1]};                    \
        __builtin_amdgcn_s_setprio(0);                                         \
        __builtin_amdgcn_sched_barrier(0);                                     \
        __syncthreads();                                                       \
    }

    for (int t = 0; t < T_STEPS; t += 2) {
        LSTM_STEP(rb0, hw1, 0)        // step t:   read buf0, write buf1
        LSTM_STEP(rb1, hw0, XSTR)     // step t+1: read buf1, write buf0
        xb += 2 * XSTR;
    }
#undef LSTM_STEP
#undef LSTM_CELL2

    // ---- epilogue: out[b][j] = b_fc[j] + sum_u h[b][u] * W_fc[j][u] ----
    *(f32x2*)&hlds[n15][u0] = hp;
    __syncthreads();
    if (tid < 256) {
        const int b = tid >> 4, j = tid & 15;
        float s = b_fc[j];
#pragma unroll 8
        for (int u = 0; u < HDIM; ++u)
            s += hlds[b][u] * W_fc[j * HDIM + u];
        out[(bbase + b) * 16 + j] = s;
    }
}

extern "C" void kernel_launch(void* const* d_in, const int* in_sizes, int n_in,
                              void* d_out, int out_size, void* d_ws, size_t ws_size,
                              hipStream_t stream) {
    const float* x    = (const float*)d_in[0];
    const float* W_ih = (const float*)d_in[1];
    const float* W_hh = (const float*)d_in[2];
    const float* b_ih = (const float*)d_in[3];
    const float* b_hh = (const float*)d_in[4];
    const float* W_fc = (const float*)d_in[5];
    const float* b_fc = (const float*)d_in[6];
    float* out = (float*)d_out;

    const int B = in_sizes[0] / (T_STEPS * I_DIM);  // 8192
    const int grid = B / BT;                         // 512 blocks (2/CU)

    lstm_mfma_kernel<<<grid, 512, 0, stream>>>(x, W_ih, W_hh, b_ih, b_hh,
                                               W_fc, b_fc, out);
}

// Round 8
// 193.818 us; speedup vs baseline: 1.1688x; 1.0048x over previous
//
#include <hip/hip_runtime.h>
#include <math.h>

#ifndef __has_builtin
#define __has_builtin(x) 0
#endif

#if __has_builtin(__builtin_amdgcn_rcpf)
#define FAST_RCP(x) __builtin_amdgcn_rcpf(x)
#else
#define FAST_RCP(x) (1.0f / (x))
#endif

#if __has_builtin(__builtin_amdgcn_exp2f)
#define FAST_EXP2(x) __builtin_amdgcn_exp2f(x)
#else
#define FAST_EXP2(x) exp2f(x)
#endif

typedef _Float16 half8 __attribute__((ext_vector_type(8)));
typedef _Float16 half2v __attribute__((ext_vector_type(2)));
typedef float f32x4 __attribute__((ext_vector_type(4)));
typedef float f32x2 __attribute__((ext_vector_type(2)));

constexpr int T_STEPS = 180;
constexpr int I_DIM   = 7;
constexpr int HDIM    = 64;
constexpr int BT      = 16;     // batch tile per block
constexpr int NCH     = 12;     // 12 chunks x 8 halfs = 96 K rows
constexpr int CH_HALF = BT * 8; // halfs per chunk slice (=128)
constexpr int XSTR    = 136;    // halfs per xstage t-slice (17 granules)

// ---- R8: exact R3 structure (measured best, 135us) + anti-phase stagger ----
// Evidence R0-R7: conflicts 10.3M->1.5M, loop vmem->0, chain 3->2 deep,
// TLP 8/16/32 waves/CU -> 156/135/176us, ILP-2, hoisting -- ALL neutral or
// worse than R3. Issue accounting: MfmaUtil 22 + VALUBusy 57 = 79% of the
// shared SIMD issue port; mix dominated by 14 quarter-rate trans/wave-step.
// The residual ~20% bubble is the barrier convoy. Last untested hypothesis:
// the two co-resident blocks PHASE-LOCK (aligned barriers -> both drain
// together). Dispatch: block i -> XCD i%8, CU slot (i/8)%32, so blocks i
// and i+256 co-reside => one-time s_sleep (~1 step interval) for bit-8
// blocks forces anti-phase; identical per-step cost preserves the offset.
// Validated structure kept verbatim from R3:
//  - chunk-major B operand, conflict-free ds_read_b128 (R1)
//  - zero-vmem steady loop; lane-blended bf0 walks pre-staged xstage (R2)
//  - gate-pair A remap -> packed dual-f32 cell math, 5 exp2 + 2 rcp /cell,
//    activation scales pre-folded into weights (R3)
// Micro: cs clamp via elementwise pk min/max (2 ops, was 4 scalar).
__global__ __launch_bounds__(512, 4) void lstm_mfma_kernel(
    const float* __restrict__ x,
    const float* __restrict__ W_ih,
    const float* __restrict__ W_hh,
    const float* __restrict__ b_ih,
    const float* __restrict__ b_hh,
    const float* __restrict__ W_fc,
    const float* __restrict__ b_fc,
    float* __restrict__ out) {
    __shared__ alignas(16) _Float16 Bbuf[2][NCH][BT][8];
    __shared__ alignas(16) _Float16 xstage[T_STEPS * XSTR];
    __shared__ alignas(16) float hlds[BT][HDIM + 4];   // fp32 h_T for epilogue

    const int tid  = (int)threadIdx.x;
    const int w    = tid >> 6;    // wave 0..7
    const int lane = tid & 63;
    const int q    = lane >> 4;   // quad 0..3
    const int n15  = lane & 15;   // batch col within tile
    const long bbase = (long)blockIdx.x * BT;

    // ---- A fragments, scale-folded, gate-pair remap ----
    half8 afrag[2][3];
#pragma unroll
    for (int pt = 0; pt < 2; ++pt) {
        const int gate = 2 * pt + ((n15 >> 1) & 1);
        const int unit = 8 * w + 2 * (n15 >> 2) + (n15 & 1);
        const int grow = gate * HDIM + unit;  // row in PyTorch [4H, *] params
        const float scl = (gate == 2) ? 2.88539008177792681472f
                                      : -1.44269504088896340736f;
#pragma unroll
        for (int kc = 0; kc < 3; ++kc) {
#pragma unroll
            for (int j = 0; j < 8; ++j) {
                const int k = kc * 32 + q * 8 + j;
                float v;
                if (k < I_DIM)            v = W_ih[grow * I_DIM + k];
                else if (k == I_DIM)      v = b_ih[grow] + b_hh[grow];
                else if (k < 8 + HDIM)    v = W_hh[grow * HDIM + (k - 8)];
                else                      v = 0.0f;
                afrag[pt][kc][j] = (_Float16)(scl * v);
            }
        }
    }

    // ---- prologue: stage all x into LDS (f16, fragment layout) ----
    for (int idx = tid; idx < BT * T_STEPS * I_DIM; idx += 512) {
        const int n = idx / (T_STEPS * I_DIM);
        const int r = idx - n * (T_STEPS * I_DIM);
        const int t = r / I_DIM, i = r - t * I_DIM;
        xstage[t * XSTR + n * 8 + i] =
            (_Float16)x[(bbase + n) * (T_STEPS * I_DIM) + r];
    }
    for (int idx = tid; idx < T_STEPS * BT; idx += 512)
        xstage[(idx >> 4) * XSTR + (idx & 15) * 8 + 7] = (_Float16)1.0f;
    for (int idx = tid; idx < 2 * NCH * CH_HALF; idx += 512)
        ((_Float16*)Bbuf)[idx] = (_Float16)0.0f;
    __syncthreads();

    // ---- anti-phase stagger: co-resident pair is {i, i+256} -> offset the
    // bit-8 block by ~1 step interval (s_sleep ~64*N cycles, N=14 ~ 900cy).
    if ((blockIdx.x >> 8) & 1) __builtin_amdgcn_s_sleep(14);

    // cell ownership: units u0 = 8w+2q, u0+1 (adjacent)
    const int u0 = 8 * w + 2 * q;

    // hoisted LDS pointers (bf0 blended: q==0 walks xstage)
    const _Float16* const rb0 = &Bbuf[0][q][n15][0];
    const _Float16* const rb1 = &Bbuf[1][q][n15][0];
    const _Float16* xb0 = (q == 0) ? &xstage[0 * XSTR + n15 * 8] : rb0;
    const _Float16* xb1 = (q == 0) ? &xstage[1 * XSTR + n15 * 8] : rb1;
    const int xadv = (q == 0) ? 2 * XSTR : 0;
    half2v* const hw0 = (half2v*)&Bbuf[0][1 + w][n15][2 * q];
    half2v* const hw1 = (half2v*)&Bbuf[1][1 + w][n15][2 * q];

    f32x2 cp = {0.0f, 0.0f};
    f32x2 hp = {0.0f, 0.0f};
    const f32x4 zq = {0.0f, 0.0f, 0.0f, 0.0f};   // hoisted MFMA C=0 operand

    // Packed cell: acc0={i0,i1,f0,f1}, acc1={g0,g1,o0,o1} (exp2-ready).
    //   A=2^i', F=2^f', E=2^g', O=2^o'  (pairwise across the 2 cells)
    //   c' = (c*P + (E-1)*Q) * rcp(P*Q),  P=(1+A)(E+1), Q=1+F
    //   h  = (C-1) * rcp((1+O)(C+1)),     C=2^(k*c') clamped
#define LSTM_CELL2(A0, A1)                                                     \
    {                                                                          \
        f32x2 Ap, Fp, Ep, Op, Rp, Cp, rD;                                      \
        Ap[0] = FAST_EXP2(A0[0]); Ap[1] = FAST_EXP2(A0[1]);                    \
        Fp[0] = FAST_EXP2(A0[2]); Fp[1] = FAST_EXP2(A0[3]);                    \
        Ep[0] = FAST_EXP2(A1[0]); Ep[1] = FAST_EXP2(A1[1]);                    \
        const f32x2 Pp = (Ap + 1.0f) * (Ep + 1.0f);                            \
        const f32x2 Qp = Fp + 1.0f;                                            \
        const f32x2 PQ = Pp * Qp;                                              \
        Rp[0] = FAST_RCP(PQ[0]); Rp[1] = FAST_RCP(PQ[1]);                      \
        cp = (cp * Pp + (Ep - 1.0f) * Qp) * Rp;                                \
        Op[0] = FAST_EXP2(A1[2]); Op[1] = FAST_EXP2(A1[3]);                    \
        f32x2 cs = cp * 2.88539008177792681472f;                               \
        cs = __builtin_elementwise_max(cs, (f32x2)(-80.0f));                   \
        cs = __builtin_elementwise_min(cs, (f32x2)(80.0f));                    \
        Cp[0] = FAST_EXP2(cs[0]); Cp[1] = FAST_EXP2(cs[1]);                    \
        const f32x2 Dp = (Op + 1.0f) * (Cp + 1.0f);                            \
        rD[0] = FAST_RCP(Dp[0]); rD[1] = FAST_RCP(Dp[1]);                      \
        hp = (Cp - 1.0f) * rD;                                                 \
    }

#define LSTM_STEP(RB, XB, HW)                                                  \
    {                                                                          \
        const half8 bf0 = *(const half8*)(XB);                                 \
        const half8 bf1 = *(const half8*)((RB) + 4 * CH_HALF);                 \
        const half8 bf2 = *(const half8*)((RB) + 8 * CH_HALF);                 \
        f32x4 acc0 = __builtin_amdgcn_mfma_f32_16x16x32_f16(afrag[0][0], bf0, zq, 0, 0, 0); \
        f32x4 acc1 = __builtin_amdgcn_mfma_f32_16x16x32_f16(afrag[1][0], bf0, zq, 0, 0, 0); \
        acc0 = __builtin_amdgcn_mfma_f32_16x16x32_f16(afrag[0][1], bf1, acc0, 0, 0, 0); \
        acc1 = __builtin_amdgcn_mfma_f32_16x16x32_f16(afrag[1][1], bf1, acc1, 0, 0, 0); \
        acc0 = __builtin_amdgcn_mfma_f32_16x16x32_f16(afrag[0][2], bf2, acc0, 0, 0, 0); \
        acc1 = __builtin_amdgcn_mfma_f32_16x16x32_f16(afrag[1][2], bf2, acc1, 0, 0, 0); \
        LSTM_CELL2(acc0, acc1)                                                 \
        *(HW) = (half2v){(_Float16)hp[0], (_Float16)hp[1]};                    \
        __syncthreads();                                                       \
    }

    for (int t = 0; t < T_STEPS; t += 2) {
        LSTM_STEP(rb0, xb0, hw1)       // read buf0 (+ xstage[t]),   write buf1
        LSTM_STEP(rb1, xb1, hw0)       // read buf1 (+ xstage[t+1]), write buf0
        xb0 += xadv;
        xb1 += xadv;
    }
#undef LSTM_STEP
#undef LSTM_CELL2

    // ---- epilogue: out[b][j] = b_fc[j] + sum_u h[b][u] * W_fc[j][u] ----
    *(f32x2*)&hlds[n15][u0] = hp;
    __syncthreads();
    if (tid < 256) {
        const int b = tid >> 4, j = tid & 15;
        float s = b_fc[j];
#pragma unroll 8
        for (int u = 0; u < HDIM; ++u)
            s += hlds[b][u] * W_fc[j * HDIM + u];
        out[(bbase + b) * 16 + j] = s;
    }
}

extern "C" void kernel_launch(void* const* d_in, const int* in_sizes, int n_in,
                              void* d_out, int out_size, void* d_ws, size_t ws_size,
                              hipStream_t stream) {
    const float* x    = (const float*)d_in[0];
    const float* W_ih = (const float*)d_in[1];
    const float* W_hh = (const float*)d_in[2];
    const float* b_ih = (const float*)d_in[3];
    const float* b_hh = (const float*)d_in[4];
    const float* W_fc = (const float*)d_in[5];
    const float* b_fc = (const float*)d_in[6];
    float* out = (float*)d_out;

    const int B = in_sizes[0] / (T_STEPS * I_DIM);  // 8192
    const int grid = B / BT;                         // 512 blocks (2/CU)

    lstm_mfma_kernel<<<grid, 512, 0, stream>>>(x, W_ih, W_hh, b_ih, b_hh,
                                               W_fc, b_fc, out);
}

// Round 9
// 191.305 us; speedup vs baseline: 1.1842x; 1.0131x over previous
//
#include <hip/hip_runtime.h>
#include <math.h>

#ifndef __has_builtin
#define __has_builtin(x) 0
#endif

#if __has_builtin(__builtin_amdgcn_rcpf)
#define FAST_RCP(x) __builtin_amdgcn_rcpf(x)
#else
#define FAST_RCP(x) (1.0f / (x))
#endif

#if __has_builtin(__builtin_amdgcn_exp2f)
#define FAST_EXP2(x) __builtin_amdgcn_exp2f(x)
#else
#define FAST_EXP2(x) exp2f(x)
#endif

typedef _Float16 half8 __attribute__((ext_vector_type(8)));
typedef _Float16 half2v __attribute__((ext_vector_type(2)));
typedef float f32x4 __attribute__((ext_vector_type(4)));
typedef float f32x2 __attribute__((ext_vector_type(2)));

constexpr int T_STEPS = 180;
constexpr int I_DIM   = 7;
constexpr int HDIM    = 64;
constexpr int BT      = 16;     // batch tile per block
constexpr int NCH     = 12;     // 12 chunks x 8 halfs = 96 K rows
constexpr int CH_HALF = BT * 8; // halfs per chunk slice (=128)
constexpr int XSTR    = 136;    // halfs per xstage t-slice (17 granules)

// ---- R9: R3-exact (measured best, 135.1us) minus falsified/dead ops ----
// Session evidence (R0-R8): conflicts 10.3M->3.0M, loop vmem->0, chain
// 3->2 deep, ILP-2, TLP 8/16/32 waves/CU (156/135/176us), setprio +
// sched_barrier, forced anti-phase s_sleep -- every structural deviation
// from this shape measured neutral or worse. Issue accounting: total
// issue demand ~78us floor at ~57-65% measured port utilization; op mix
// floored (5 exp2 + 2 rcp/cell is the LSTM minimum; 6 MFMA/wave-step
// minimal; LDS reads conflict-free; zero steady-state vmem). Residual
// bubble = the barrier-locked recurrence latency chain that 2 co-resident
// blocks/CU cannot fully hide; grid (512 blocks) pins co-residency at 2.
// Deltas vs R8: s_sleep removed (falsified); lower cs clamp removed
// (exp2(-big) flushes to 0 -> h = -1/(1+O), the exact tanh -> -1 limit;
// only the upper bound is needed to block inf -> NaN).
// Validated structure:
//  - chunk-major B operand, conflict-free ds_read_b128 (R1)
//  - zero-vmem steady loop; lane-blended bf0 walks pre-staged xstage (R2)
//  - gate-pair A remap -> packed dual-f32 cell math, 5 exp2 + 2 rcp /cell,
//    activation scales pre-folded into weights (R3)
// A-row remap: tile pt, row r -> param row gate*64 + unit,
//   gate = 2*pt + ((r>>1)&1), unit = 8w + 2*(r>>2) + (r&1)
// => lane (q,n15): acc0 = {i(u0),i(u0+1),f(u0),f(u0+1)}, acc1 = {g..,o..},
//    u0 = 8w+2q; h stored as ONE packed b32 write.
__global__ __launch_bounds__(512, 4) void lstm_mfma_kernel(
    const float* __restrict__ x,
    const float* __restrict__ W_ih,
    const float* __restrict__ W_hh,
    const float* __restrict__ b_ih,
    const float* __restrict__ b_hh,
    const float* __restrict__ W_fc,
    const float* __restrict__ b_fc,
    float* __restrict__ out) {
    __shared__ alignas(16) _Float16 Bbuf[2][NCH][BT][8];
    __shared__ alignas(16) _Float16 xstage[T_STEPS * XSTR];
    __shared__ alignas(16) float hlds[BT][HDIM + 4];   // fp32 h_T for epilogue

    const int tid  = (int)threadIdx.x;
    const int w    = tid >> 6;    // wave 0..7
    const int lane = tid & 63;
    const int q    = lane >> 4;   // quad 0..3
    const int n15  = lane & 15;   // batch col within tile
    const long bbase = (long)blockIdx.x * BT;

    // ---- A fragments, scale-folded, gate-pair remap ----
    half8 afrag[2][3];
#pragma unroll
    for (int pt = 0; pt < 2; ++pt) {
        const int gate = 2 * pt + ((n15 >> 1) & 1);
        const int unit = 8 * w + 2 * (n15 >> 2) + (n15 & 1);
        const int grow = gate * HDIM + unit;  // row in PyTorch [4H, *] params
        const float scl = (gate == 2) ? 2.88539008177792681472f
                                      : -1.44269504088896340736f;
#pragma unroll
        for (int kc = 0; kc < 3; ++kc) {
#pragma unroll
            for (int j = 0; j < 8; ++j) {
                const int k = kc * 32 + q * 8 + j;
                float v;
                if (k < I_DIM)            v = W_ih[grow * I_DIM + k];
                else if (k == I_DIM)      v = b_ih[grow] + b_hh[grow];
                else if (k < 8 + HDIM)    v = W_hh[grow * HDIM + (k - 8)];
                else                      v = 0.0f;
                afrag[pt][kc][j] = (_Float16)(scl * v);
            }
        }
    }

    // ---- prologue: stage all x into LDS (f16, fragment layout) ----
    for (int idx = tid; idx < BT * T_STEPS * I_DIM; idx += 512) {
        const int n = idx / (T_STEPS * I_DIM);
        const int r = idx - n * (T_STEPS * I_DIM);
        const int t = r / I_DIM, i = r - t * I_DIM;
        xstage[t * XSTR + n * 8 + i] =
            (_Float16)x[(bbase + n) * (T_STEPS * I_DIM) + r];
    }
    for (int idx = tid; idx < T_STEPS * BT; idx += 512)
        xstage[(idx >> 4) * XSTR + (idx & 15) * 8 + 7] = (_Float16)1.0f;
    for (int idx = tid; idx < 2 * NCH * CH_HALF; idx += 512)
        ((_Float16*)Bbuf)[idx] = (_Float16)0.0f;
    __syncthreads();

    // cell ownership: units u0 = 8w+2q, u0+1 (adjacent)
    const int u0 = 8 * w + 2 * q;

    // hoisted LDS pointers (bf0 blended: q==0 walks xstage)
    const _Float16* const rb0 = &Bbuf[0][q][n15][0];
    const _Float16* const rb1 = &Bbuf[1][q][n15][0];
    const _Float16* xb0 = (q == 0) ? &xstage[0 * XSTR + n15 * 8] : rb0;
    const _Float16* xb1 = (q == 0) ? &xstage[1 * XSTR + n15 * 8] : rb1;
    const int xadv = (q == 0) ? 2 * XSTR : 0;
    half2v* const hw0 = (half2v*)&Bbuf[0][1 + w][n15][2 * q];
    half2v* const hw1 = (half2v*)&Bbuf[1][1 + w][n15][2 * q];

    f32x2 cp = {0.0f, 0.0f};
    f32x2 hp = {0.0f, 0.0f};
    const f32x4 zq = {0.0f, 0.0f, 0.0f, 0.0f};   // hoisted MFMA C=0 operand

    // Packed cell: acc0={i0,i1,f0,f1}, acc1={g0,g1,o0,o1} (exp2-ready).
    //   A=2^i', F=2^f', E=2^g', O=2^o'  (pairwise across the 2 cells)
    //   c' = (c*P + (E-1)*Q) * rcp(P*Q),  P=(1+A)(E+1), Q=1+F
    //   h  = (C-1) * rcp((1+O)(C+1)),     C=2^(k*c') clamped above only
    //   (exp2 underflow flushes to 0 -> h -> -1/(1+O), the exact limit)
#define LSTM_CELL2(A0, A1)                                                     \
    {                                                                          \
        f32x2 Ap, Fp, Ep, Op, Rp, Cp, rD;                                      \
        Ap[0] = FAST_EXP2(A0[0]); Ap[1] = FAST_EXP2(A0[1]);                    \
        Fp[0] = FAST_EXP2(A0[2]); Fp[1] = FAST_EXP2(A0[3]);                    \
        Ep[0] = FAST_EXP2(A1[0]); Ep[1] = FAST_EXP2(A1[1]);                    \
        const f32x2 Pp = (Ap + 1.0f) * (Ep + 1.0f);                            \
        const f32x2 Qp = Fp + 1.0f;                                            \
        const f32x2 PQ = Pp * Qp;                                              \
        Rp[0] = FAST_RCP(PQ[0]); Rp[1] = FAST_RCP(PQ[1]);                      \
        cp = (cp * Pp + (Ep - 1.0f) * Qp) * Rp;                                \
        Op[0] = FAST_EXP2(A1[2]); Op[1] = FAST_EXP2(A1[3]);                    \
        f32x2 cs = cp * 2.88539008177792681472f;                               \
        cs = __builtin_elementwise_min(cs, (f32x2)(80.0f));                    \
        Cp[0] = FAST_EXP2(cs[0]); Cp[1] = FAST_EXP2(cs[1]);                    \
        const f32x2 Dp = (Op + 1.0f) * (Cp + 1.0f);                            \
        rD[0] = FAST_RCP(Dp[0]); rD[1] = FAST_RCP(Dp[1]);                      \
        hp = (Cp - 1.0f) * rD;                                                 \
    }

#define LSTM_STEP(RB, XB, HW)                                                  \
    {                                                                          \
        const half8 bf0 = *(const half8*)(XB);                                 \
        const half8 bf1 = *(const half8*)((RB) + 4 * CH_HALF);                 \
        const half8 bf2 = *(const half8*)((RB) + 8 * CH_HALF);                 \
        f32x4 acc0 = __builtin_amdgcn_mfma_f32_16x16x32_f16(afrag[0][0], bf0, zq, 0, 0, 0); \
        f32x4 acc1 = __builtin_amdgcn_mfma_f32_16x16x32_f16(afrag[1][0], bf0, zq, 0, 0, 0); \
        acc0 = __builtin_amdgcn_mfma_f32_16x16x32_f16(afrag[0][1], bf1, acc0, 0, 0, 0); \
        acc1 = __builtin_amdgcn_mfma_f32_16x16x32_f16(afrag[1][1], bf1, acc1, 0, 0, 0); \
        acc0 = __builtin_amdgcn_mfma_f32_16x16x32_f16(afrag[0][2], bf2, acc0, 0, 0, 0); \
        acc1 = __builtin_amdgcn_mfma_f32_16x16x32_f16(afrag[1][2], bf2, acc1, 0, 0, 0); \
        LSTM_CELL2(acc0, acc1)                                                 \
        *(HW) = (half2v){(_Float16)hp[0], (_Float16)hp[1]};                    \
        __syncthreads();                                                       \
    }

    for (int t = 0; t < T_STEPS; t += 2) {
        LSTM_STEP(rb0, xb0, hw1)       // read buf0 (+ xstage[t]),   write buf1
        LSTM_STEP(rb1, xb1, hw0)       // read buf1 (+ xstage[t+1]), write buf0
        xb0 += xadv;
        xb1 += xadv;
    }
#undef LSTM_STEP
#undef LSTM_CELL2

    // ---- epilogue: out[b][j] = b_fc[j] + sum_u h[b][u] * W_fc[j][u] ----
    *(f32x2*)&hlds[n15][u0] = hp;
    __syncthreads();
    if (tid < 256) {
        const int b = tid >> 4, j = tid & 15;
        float s = b_fc[j];
#pragma unroll 8
        for (int u = 0; u < HDIM; ++u)
            s += hlds[b][u] * W_fc[j * HDIM + u];
        out[(bbase + b) * 16 + j] = s;
    }
}

extern "C" void kernel_launch(void* const* d_in, const int* in_sizes, int n_in,
                              void* d_out, int out_size, void* d_ws, size_t ws_size,
                              hipStream_t stream) {
    const float* x    = (const float*)d_in[0];
    const float* W_ih = (const float*)d_in[1];
    const float* W_hh = (const float*)d_in[2];
    const float* b_ih = (const float*)d_in[3];
    const float* b_hh = (const float*)d_in[4];
    const float* W_fc = (const float*)d_in[5];
    const float* b_fc = (const float*)d_in[6];
    float* out = (float*)d_out;

    const int B = in_sizes[0] / (T_STEPS * I_DIM);  // 8192
    const int grid = B / BT;                         // 512 blocks (2/CU)

    lstm_mfma_kernel<<<grid, 512, 0, stream>>>(x, W_ih, W_hh, b_ih, b_hh,
                                               W_fc, b_fc, out);
}